// Round 3
// baseline (292.239 us; speedup 1.0000x reference)
//
#include <hip/hip_runtime.h>
#include <hip/hip_bf16.h>

#define BB 64
#define CC 64
#define TT_ 128
#define VV 25
#define RR 8
#define TS_ 9
#define OO 64

typedef __hip_bfloat16 bf16;

// ---------------------------------------------------------------------------
// Kernel 1: xm[b,c,v] = mean over t of x[b,c,t,v]   (fp32 in, fp32 out)
// ---------------------------------------------------------------------------
__global__ __launch_bounds__(256) void k_mean(const float* __restrict__ x,
                                              float* __restrict__ xm) {
    int idx = blockIdx.x * 256 + threadIdx.x;       // 0 .. B*C*V-1
    if (idx >= BB * CC * VV) return;
    int v  = idx % VV;
    int bc = idx / VV;
    const float* p = x + (size_t)bc * TT_ * VV + v;
    float s = 0.f;
    #pragma unroll 8
    for (int t = 0; t < TT_; t++) s += p[t * VV];
    xm[idx] = s * (1.0f / TT_);
}

// ---------------------------------------------------------------------------
// Kernel 2: prep — transpose W3 to [c][o], copy b3
// ---------------------------------------------------------------------------
__global__ __launch_bounds__(256) void k_prep(const float* __restrict__ W3,
                                              const float* __restrict__ b3,
                                              float* __restrict__ w3t,
                                              float* __restrict__ b3f) {
    int idx = blockIdx.x * 256 + threadIdx.x;
    if (idx < OO * CC) {
        int o = idx / CC, c = idx % CC;
        w3t[c * OO + o] = W3[idx];
    }
    if (idx < OO) b3f[idx] = b3[idx];
}

// ---------------------------------------------------------------------------
// Kernel 3: rel[b][v][i][r] = tanh(x1[b,r,v] - x2[b,r,i])   (fp32)
//   x1[b,r,v] = sum_c W1[r,c]*xm[b,c,v] + b1[r]   (xm already has /T)
// ---------------------------------------------------------------------------
__global__ __launch_bounds__(256) void k_rel(const float* __restrict__ xm,
                                             const float* __restrict__ W1,
                                             const float* __restrict__ b1,
                                             const float* __restrict__ W2,
                                             const float* __restrict__ b2,
                                             float* __restrict__ rel) {
    __shared__ float x1s[RR][VV];
    __shared__ float x2s[RR][VV];
    int b = blockIdx.x, tid = threadIdx.x;
    for (int idx = tid; idx < RR * VV; idx += 256) {
        int r = idx / VV, v = idx % VV;
        float s1 = b1[r], s2 = b2[r];
        for (int c = 0; c < CC; c++) {
            float xv = xm[(b * CC + c) * VV + v];
            s1 += W1[r * CC + c] * xv;
            s2 += W2[r * CC + c] * xv;
        }
        x1s[r][v] = s1;
        x2s[r][v] = s2;
    }
    __syncthreads();
    float* relb = rel + (size_t)b * VV * VV * RR;
    for (int idx = tid; idx < VV * VV * RR; idx += 256) {
        int r = idx % RR;
        int i = (idx / RR) % VV;
        int v = idx / (RR * VV);
        relb[idx] = tanhf(x1s[r][v] - x2s[r][i]);   // idx == v*200 + i*8 + r
    }
}

// ---------------------------------------------------------------------------
// Kernel 4: z[b,c,t,i] = sum_{v,k} xpad[v][t+k] * Ad[k][v][i]   -> bf16
//   Ad[k][v][i] = sum_r W4[c*9+k,r]*rel[b,v,i,r] + b4[c*9+k] + A[v,i]
//   One block per (b,c). 256 threads.
// ---------------------------------------------------------------------------
__global__ __launch_bounds__(256) void k_z(const float* __restrict__ x,
                                           const float* __restrict__ Ag,
                                           const float* __restrict__ W4,
                                           const float* __restrict__ b4,
                                           const float* __restrict__ rel,
                                           bf16* __restrict__ zws) {
    __shared__ float xpad[VV][136];      // [v][t'] with t' = t + 8, zeros at 0..7
    __shared__ float adl[VV * VV * 12];  // [(v*25+i)*12 + k], k padded to 12
    __shared__ float w4l[TS_][RR];
    __shared__ float b4l[TS_];

    int tid = threadIdx.x;
    int b = blockIdx.x / CC, c = blockIdx.x % CC;

    if (tid < TS_ * RR)
        w4l[tid / RR][tid % RR] = W4[(c * TS_ + tid / RR) * RR + tid % RR];
    if (tid < TS_) b4l[tid] = b4[c * TS_ + tid];

    for (int idx = tid; idx < VV * 8; idx += 256) xpad[idx / 8][idx % 8] = 0.f;
    const float* xb = x + (size_t)(b * CC + c) * TT_ * VV;
    for (int idx = tid; idx < TT_ * VV; idx += 256)
        xpad[idx % VV][idx / VV + 8] = xb[idx];
    __syncthreads();

    // Ad compute: each task = one (v,i), all 9 k
    const float* relb = rel + (size_t)b * VV * VV * RR;
    for (int idx = tid; idx < VV * VV; idx += 256) {
        int v = idx / VV, i = idx % VV;
        const float4* r4 = (const float4*)(relb + (size_t)idx * RR);
        float4 ra = r4[0], rb = r4[1];
        float av = Ag[v * VV + i];
        float* dst = &adl[idx * 12];
        #pragma unroll
        for (int k = 0; k < TS_; k++) {
            float acc = b4l[k] + av;
            acc += w4l[k][0] * ra.x + w4l[k][1] * ra.y + w4l[k][2] * ra.z + w4l[k][3] * ra.w;
            acc += w4l[k][4] * rb.x + w4l[k][5] * rb.y + w4l[k][6] * rb.z + w4l[k][7] * rb.w;
            dst[k] = acc;
        }
    }
    __syncthreads();

    // z compute: 200 active threads, thread = (i, t-block of 16)
    float acc[16];
    int i_ = 0, t0_ = 0;
    if (tid < 200) {
        i_  = tid >> 3;          // 0..24
        t0_ = (tid & 7) << 4;    // 0,16,...,112
        #pragma unroll
        for (int t = 0; t < 16; t++) acc[t] = 0.f;
        for (int v = 0; v < VV; v++) {
            float xr[24];
            const float4* xp4 = (const float4*)&xpad[v][t0_];  // t0_%4==0
            #pragma unroll
            for (int q = 0; q < 6; q++) {
                float4 f = xp4[q];
                xr[4 * q] = f.x; xr[4 * q + 1] = f.y; xr[4 * q + 2] = f.z; xr[4 * q + 3] = f.w;
            }
            const float* ad = &adl[(v * VV + i_) * 12];
            float4 a0 = *(const float4*)ad;
            float4 a1 = *(const float4*)(ad + 4);
            float adv[9] = {a0.x, a0.y, a0.z, a0.w, a1.x, a1.y, a1.z, a1.w, ad[8]};
            #pragma unroll
            for (int k = 0; k < 9; k++)
                #pragma unroll
                for (int t = 0; t < 16; t++)
                    acc[t] += xr[t + k] * adv[k];
        }
    }
    __syncthreads();
    // stage z tile in LDS (reuse adl) for coalesced bf16 store
    if (tid < 200) {
        #pragma unroll
        for (int t = 0; t < 16; t++) adl[(t0_ + t) * VV + i_] = acc[t];
    }
    __syncthreads();
    bf16* zb = zws + (size_t)(b * CC + c) * TT_ * VV;
    for (int idx = tid; idx < TT_ * VV; idx += 256)
        zb[idx] = __float2bfloat16(adl[idx]);
}

// ---------------------------------------------------------------------------
// Kernel 5: out[b,o,t,j] = sum_c W3[o,c]*z[b,c,t,j] + b3[o]   -> FP32 out
//   Grid: B * 25 blocks; each block = one b, 128 contiguous (t*V+j) positions.
// ---------------------------------------------------------------------------
__global__ __launch_bounds__(256) void k_conv3(const bf16* __restrict__ zws,
                                               const float* __restrict__ w3t,
                                               const float* __restrict__ b3f,
                                               float* __restrict__ out) {
    __shared__ float zl[CC][128];    // 32 KB
    __shared__ float w3l[CC * OO];   // 16 KB, [c][o]
    int tid = threadIdx.x;
    int b = blockIdx.x / 25, tile = blockIdx.x % 25;
    int tj0 = tile * 128;

    for (int idx = tid; idx < CC * OO; idx += 256) w3l[idx] = w3t[idx];
    for (int idx = tid; idx < CC * 128; idx += 256) {
        int c = idx >> 7, j = idx & 127;
        zl[c][j] = __bfloat162float(zws[(size_t)(b * CC + c) * (TT_ * VV) + tj0 + j]);
    }
    __syncthreads();

    int og = tid >> 5, tg = tid & 31;    // 8 o-groups x 32 tj-groups
    int o0 = og * 8, j0 = tg * 4;
    float accv[8][4];
    #pragma unroll
    for (int a = 0; a < 8; a++)
        #pragma unroll
        for (int q = 0; q < 4; q++) accv[a][q] = 0.f;

    for (int c = 0; c < CC; c++) {
        float4 zv = *(const float4*)&zl[c][j0];
        float4 wa = *(const float4*)&w3l[c * OO + o0];
        float4 wb = *(const float4*)&w3l[c * OO + o0 + 4];
        float zq[4] = {zv.x, zv.y, zv.z, zv.w};
        float wo[8] = {wa.x, wa.y, wa.z, wa.w, wb.x, wb.y, wb.z, wb.w};
        #pragma unroll
        for (int a = 0; a < 8; a++)
            #pragma unroll
            for (int q = 0; q < 4; q++) accv[a][q] += wo[a] * zq[q];
    }

    #pragma unroll
    for (int a = 0; a < 8; a++) {
        int o = o0 + a;
        float bo = b3f[o];
        float4 res;
        res.x = accv[a][0] + bo;
        res.y = accv[a][1] + bo;
        res.z = accv[a][2] + bo;
        res.w = accv[a][3] + bo;
        *(float4*)(out + ((size_t)(b * OO + o)) * (TT_ * VV) + tj0 + j0) = res;
    }
}

// ---------------------------------------------------------------------------
extern "C" void kernel_launch(void* const* d_in, const int* in_sizes, int n_in,
                              void* d_out, int out_size, void* d_ws, size_t ws_size,
                              hipStream_t stream) {
    const float* x  = (const float*)d_in[0];
    const float* A  = (const float*)d_in[1];
    const float* W1 = (const float*)d_in[2];
    const float* b1 = (const float*)d_in[3];
    const float* W2 = (const float*)d_in[4];
    const float* b2 = (const float*)d_in[5];
    const float* W4 = (const float*)d_in[6];
    const float* b4 = (const float*)d_in[7];
    const float* W3 = (const float*)d_in[8];
    const float* b3 = (const float*)d_in[9];
    float* out = (float*)d_out;          // reference output dtype is float32

    // workspace layout (bytes)
    char* ws = (char*)d_ws;
    float* xm   = (float*)(ws);                         // 102400 * 4 = 409600
    float* rel  = (float*)(ws + 409600);                // 320000 * 4 = 1280000
    float* w3t  = (float*)(ws + 1689600);               // 4096 * 4 = 16384
    float* b3f  = (float*)(ws + 1705984);               // 64 * 4 = 256
    bf16*  zws  = (bf16*)(ws + 1706240);                // 13107200 * 2 = 26214400

    k_mean <<<(BB * CC * VV + 255) / 256, 256, 0, stream>>>(x, xm);
    k_prep <<<(OO * CC + 255) / 256,      256, 0, stream>>>(W3, b3, w3t, b3f);
    k_rel  <<<BB,                          256, 0, stream>>>(xm, W1, b1, W2, b2, rel);
    k_z    <<<BB * CC,                     256, 0, stream>>>(x, A, W4, b4, rel, zws);
    k_conv3<<<BB * 25,                     256, 0, stream>>>(zws, w3t, b3f, out);
}

// Round 4
// 265.449 us; speedup vs baseline: 1.1009x; 1.1009x over previous
//
#include <hip/hip_runtime.h>
#include <hip/hip_bf16.h>

#define BB 64
#define CC 64
#define TT_ 128
#define VV 25
#define RR 8
#define TS_ 9
#define OO 64
#define XROW 172   // physical row stride of xpad (43 quads, odd -> staggers banks)

typedef __hip_bfloat16 bf16;

// ---------------------------------------------------------------------------
// Kernel 1: xm[b,c,v] = mean over t of x[b,c,t,v]. Block per (b,c), coalesced.
// ---------------------------------------------------------------------------
__global__ __launch_bounds__(256) void k_mean(const float* __restrict__ x,
                                              float* __restrict__ xm) {
    __shared__ float sm[256];
    int bc = blockIdx.x;
    int tid = threadIdx.x;
    const float* p = x + (size_t)bc * TT_ * VV;
    float s = 0.f;
    if (tid < 250) {
        // lane l covers elements l, l+250, ... (t = l/25 + 10j, v = l%25), coalesced
        for (int off = tid; off < TT_ * VV; off += 250) s += p[off];
    }
    sm[tid] = s;
    __syncthreads();
    if (tid < VV) {
        float tot = 0.f;
        #pragma unroll
        for (int g = 0; g < 10; g++) tot += sm[g * VV + tid];
        xm[bc * VV + tid] = tot * (1.0f / TT_);
    }
}

// ---------------------------------------------------------------------------
// Kernel 2: prep — transpose W3 to [c][o], copy b3
// ---------------------------------------------------------------------------
__global__ __launch_bounds__(256) void k_prep(const float* __restrict__ W3,
                                              const float* __restrict__ b3,
                                              float* __restrict__ w3t,
                                              float* __restrict__ b3f) {
    int idx = blockIdx.x * 256 + threadIdx.x;
    if (idx < OO * CC) {
        int o = idx / CC, c = idx % CC;
        w3t[c * OO + o] = W3[idx];
    }
    if (idx < OO) b3f[idx] = b3[idx];
}

// ---------------------------------------------------------------------------
// Kernel 3: rel[b][v][i][r] = tanh(x1[b,r,v] - x2[b,r,i])   (fp32)
// ---------------------------------------------------------------------------
__global__ __launch_bounds__(256) void k_rel(const float* __restrict__ xm,
                                             const float* __restrict__ W1,
                                             const float* __restrict__ b1,
                                             const float* __restrict__ W2,
                                             const float* __restrict__ b2,
                                             float* __restrict__ rel) {
    __shared__ float x1s[RR][VV];
    __shared__ float x2s[RR][VV];
    int b = blockIdx.x, tid = threadIdx.x;
    for (int idx = tid; idx < RR * VV; idx += 256) {
        int r = idx / VV, v = idx % VV;
        float s1 = b1[r], s2 = b2[r];
        for (int c = 0; c < CC; c++) {
            float xv = xm[(b * CC + c) * VV + v];
            s1 += W1[r * CC + c] * xv;
            s2 += W2[r * CC + c] * xv;
        }
        x1s[r][v] = s1;
        x2s[r][v] = s2;
    }
    __syncthreads();
    float* relb = rel + (size_t)b * VV * VV * RR;
    for (int idx = tid; idx < VV * VV * RR; idx += 256) {
        int r = idx % RR;
        int i = (idx / RR) % VV;
        int v = idx / (RR * VV);
        relb[idx] = tanhf(x1s[r][v] - x2s[r][i]);   // idx == v*200 + i*8 + r
    }
}

// ---------------------------------------------------------------------------
// Kernel 4: z[b,c,t,i] = sum_{v,k} xpad[v][t+k] * Ad[k][v][i]   -> bf16
//   Bank-conflict-free layouts:
//     xpad: phys col = c + 4*(c>>4)  (gap quad every 16) -> thread-k reads at
//           20k mod 32, all 8 bank-quads distinct.
//     adl:  stride 8, taps 0..7 written as two b128; tap 8 in compact adl8.
//     z-stage: +(t0>>2) skew.
// ---------------------------------------------------------------------------
__global__ __launch_bounds__(256) void k_z(const float* __restrict__ x,
                                           const float* __restrict__ Ag,
                                           const float* __restrict__ W4,
                                           const float* __restrict__ b4,
                                           const float* __restrict__ rel,
                                           bf16* __restrict__ zws) {
    __shared__ __align__(16) float xpad[VV * XROW];   // 17200 B
    __shared__ __align__(16) float adl[VV * VV * 8];  // 20000 B (also z-stage)
    __shared__ float adl8[VV * VV];                   // 2500 B
    __shared__ float w4l[TS_][RR];
    __shared__ float b4l[TS_];

    int tid = threadIdx.x;
    int b = blockIdx.x / CC, c = blockIdx.x % CC;

    if (tid < TS_ * RR)
        w4l[tid / RR][tid % RR] = W4[(c * TS_ + tid / RR) * RR + tid % RR];
    if (tid < TS_) b4l[tid] = b4[c * TS_ + tid];

    // zero-fill logical cols 0..7 (phys == logical there)
    for (int idx = tid; idx < VV * 8; idx += 256)
        xpad[(idx / 8) * XROW + (idx % 8)] = 0.f;
    const float* xb = x + (size_t)(b * CC + c) * TT_ * VV;
    for (int idx = tid; idx < TT_ * VV; idx += 256) {
        int v  = idx % VV;
        int cl = idx / VV + 8;               // logical col 8..135
        int pc = cl + ((cl >> 4) << 2);      // gap-swizzled physical col
        xpad[v * XROW + pc] = xb[idx];
    }
    __syncthreads();

    // Ad phase: task = one (v,i), all 9 taps
    const float* relb = rel + (size_t)b * VV * VV * RR;
    for (int idx = tid; idx < VV * VV; idx += 256) {
        int v = idx / VV, i = idx % VV;
        const float4* r4 = (const float4*)(relb + (size_t)idx * RR);
        float4 ra = r4[0], rb_ = r4[1];
        float av = Ag[v * VV + i];
        float dk[TS_];
        #pragma unroll
        for (int k = 0; k < TS_; k++) {
            float a2 = b4l[k] + av;
            a2 += w4l[k][0] * ra.x + w4l[k][1] * ra.y + w4l[k][2] * ra.z + w4l[k][3] * ra.w;
            a2 += w4l[k][4] * rb_.x + w4l[k][5] * rb_.y + w4l[k][6] * rb_.z + w4l[k][7] * rb_.w;
            dk[k] = a2;
        }
        float4 d0 = make_float4(dk[0], dk[1], dk[2], dk[3]);
        float4 d1 = make_float4(dk[4], dk[5], dk[6], dk[7]);
        *(float4*)&adl[idx * 8]     = d0;
        *(float4*)&adl[idx * 8 + 4] = d1;
        adl8[idx] = dk[8];
    }
    __syncthreads();

    // z phase: 200 active threads, thread = (i, t-block of 16)
    float acc[16];
    int i_ = 0, t0_ = 0;
    if (tid < 200) {
        i_  = tid >> 3;                       // 0..24
        t0_ = (tid & 7) << 4;                 // 0,16,...,112
        int xbase = t0_ + (t0_ >> 2);         // phys col of logical t0_
        #pragma unroll
        for (int t = 0; t < 16; t++) acc[t] = 0.f;
        for (int v = 0; v < VV; v++) {
            const float* xr0 = &xpad[v * XROW + xbase];
            float4 f0 = *(const float4*)(xr0);
            float4 f1 = *(const float4*)(xr0 + 4);
            float4 f2 = *(const float4*)(xr0 + 8);
            float4 f3 = *(const float4*)(xr0 + 12);
            float4 f4 = *(const float4*)(xr0 + 20);   // logical t0_+16..19
            float4 f5 = *(const float4*)(xr0 + 24);   // logical t0_+20..23
            float xr[24] = {f0.x, f0.y, f0.z, f0.w, f1.x, f1.y, f1.z, f1.w,
                            f2.x, f2.y, f2.z, f2.w, f3.x, f3.y, f3.z, f3.w,
                            f4.x, f4.y, f4.z, f4.w, f5.x, f5.y, f5.z, f5.w};
            const float* ad = &adl[(v * VV + i_) * 8];
            float4 a0 = *(const float4*)ad;
            float4 a1 = *(const float4*)(ad + 4);
            float adv[9] = {a0.x, a0.y, a0.z, a0.w, a1.x, a1.y, a1.z, a1.w,
                            adl8[v * VV + i_]};
            #pragma unroll
            for (int k = 0; k < 9; k++)
                #pragma unroll
                for (int t = 0; t < 16; t++)
                    acc[t] += xr[t + k] * adv[k];
        }
    }
    __syncthreads();
    // stage z tile in LDS (reuse adl) with bank skew, then coalesced bf16 store
    if (tid < 200) {
        int zoff = t0_ >> 2;
        #pragma unroll
        for (int t = 0; t < 16; t++) adl[(t0_ + t) * VV + i_ + zoff] = acc[t];
    }
    __syncthreads();
    bf16* zb = zws + (size_t)(b * CC + c) * TT_ * VV;
    for (int idx = tid; idx < TT_ * VV; idx += 256) {
        int tq = idx / VV;
        zb[idx] = __float2bfloat16(adl[idx + ((tq >> 4) << 2)]);
    }
}

// ---------------------------------------------------------------------------
// Kernel 5: out[b,o,t,j] = sum_c W3[o,c]*z[b,c,t,j] + b3[o]   -> FP32 out
// ---------------------------------------------------------------------------
__global__ __launch_bounds__(256) void k_conv3(const bf16* __restrict__ zws,
                                               const float* __restrict__ w3t,
                                               const float* __restrict__ b3f,
                                               float* __restrict__ out) {
    __shared__ float zl[CC][128];    // 32 KB
    __shared__ float w3l[CC * OO];   // 16 KB, [c][o]
    int tid = threadIdx.x;
    int b = blockIdx.x / 25, tile = blockIdx.x % 25;
    int tj0 = tile * 128;

    for (int idx = tid; idx < CC * OO; idx += 256) w3l[idx] = w3t[idx];
    for (int idx = tid; idx < CC * 128; idx += 256) {
        int c = idx >> 7, j = idx & 127;
        zl[c][j] = __bfloat162float(zws[(size_t)(b * CC + c) * (TT_ * VV) + tj0 + j]);
    }
    __syncthreads();

    int og = tid >> 5, tg = tid & 31;    // 8 o-groups x 32 tj-groups
    int o0 = og * 8, j0 = tg * 4;
    float accv[8][4];
    #pragma unroll
    for (int a = 0; a < 8; a++)
        #pragma unroll
        for (int q = 0; q < 4; q++) accv[a][q] = 0.f;

    for (int c = 0; c < CC; c++) {
        float4 zv = *(const float4*)&zl[c][j0];
        float4 wa = *(const float4*)&w3l[c * OO + o0];
        float4 wb = *(const float4*)&w3l[c * OO + o0 + 4];
        float zq[4] = {zv.x, zv.y, zv.z, zv.w};
        float wo[8] = {wa.x, wa.y, wa.z, wa.w, wb.x, wb.y, wb.z, wb.w};
        #pragma unroll
        for (int a = 0; a < 8; a++)
            #pragma unroll
            for (int q = 0; q < 4; q++) accv[a][q] += wo[a] * zq[q];
    }

    #pragma unroll
    for (int a = 0; a < 8; a++) {
        int o = o0 + a;
        float bo = b3f[o];
        float4 res;
        res.x = accv[a][0] + bo;
        res.y = accv[a][1] + bo;
        res.z = accv[a][2] + bo;
        res.w = accv[a][3] + bo;
        *(float4*)(out + ((size_t)(b * OO + o)) * (TT_ * VV) + tj0 + j0) = res;
    }
}

// ---------------------------------------------------------------------------
extern "C" void kernel_launch(void* const* d_in, const int* in_sizes, int n_in,
                              void* d_out, int out_size, void* d_ws, size_t ws_size,
                              hipStream_t stream) {
    const float* x  = (const float*)d_in[0];
    const float* A  = (const float*)d_in[1];
    const float* W1 = (const float*)d_in[2];
    const float* b1 = (const float*)d_in[3];
    const float* W2 = (const float*)d_in[4];
    const float* b2 = (const float*)d_in[5];
    const float* W4 = (const float*)d_in[6];
    const float* b4 = (const float*)d_in[7];
    const float* W3 = (const float*)d_in[8];
    const float* b3 = (const float*)d_in[9];
    float* out = (float*)d_out;

    // workspace layout (bytes)
    char* ws = (char*)d_ws;
    float* xm   = (float*)(ws);                         // 102400 * 4
    float* rel  = (float*)(ws + 409600);                // 320000 * 4
    float* w3t  = (float*)(ws + 1689600);               // 4096 * 4
    float* b3f  = (float*)(ws + 1705984);               // 64 * 4
    bf16*  zws  = (bf16*)(ws + 1706240);                // 13107200 * 2

    k_mean <<<BB * CC,                     256, 0, stream>>>(x, xm);
    k_prep <<<(OO * CC + 255) / 256,      256, 0, stream>>>(W3, b3, w3t, b3f);
    k_rel  <<<BB,                          256, 0, stream>>>(xm, W1, b1, W2, b2, rel);
    k_z    <<<BB * CC,                     256, 0, stream>>>(x, A, W4, b4, rel, zws);
    k_conv3<<<BB * 25,                     256, 0, stream>>>(zws, w3t, b3f, out);
}

// Round 5
// 194.835 us; speedup vs baseline: 1.4999x; 1.3624x over previous
//
#include <hip/hip_runtime.h>
#include <hip/hip_bf16.h>

#define BB 64
#define CC 64
#define TT_ 128
#define VV 25
#define RR 8
#define TS_ 9
#define OO 64

typedef __hip_bfloat16 bf16;
typedef __attribute__((ext_vector_type(8))) short short8;
typedef __attribute__((ext_vector_type(4))) float f32x4;

__device__ __forceinline__ unsigned short f2b(float f) {
    bf16 h = __float2bfloat16(f);
    return __builtin_bit_cast(unsigned short, h);
}

// ---------------------------------------------------------------------------
// Kernel 1: xm[b,c,v] = mean over t of x[b,c,t,v]. Block per (b,c), coalesced.
// ---------------------------------------------------------------------------
__global__ __launch_bounds__(256) void k_mean(const float* __restrict__ x,
                                              float* __restrict__ xm) {
    __shared__ float sm[256];
    int bc = blockIdx.x;
    int tid = threadIdx.x;
    const float* p = x + (size_t)bc * TT_ * VV;
    float s = 0.f;
    if (tid < 250) {
        for (int off = tid; off < TT_ * VV; off += 250) s += p[off];
    }
    sm[tid] = s;
    __syncthreads();
    if (tid < VV) {
        float tot = 0.f;
        #pragma unroll
        for (int g = 0; g < 10; g++) tot += sm[g * VV + tid];
        xm[bc * VV + tid] = tot * (1.0f / TT_);
    }
}

// ---------------------------------------------------------------------------
// Kernel 2: rel + (folded) W3-transpose prep.
//   blocks 0..63:  rel[b][v][i][r] = tanh(x1[b,r,v] - x2[b,r,i])
//   blocks 64..79: w3t[c][o] = W3[o][c]; b3f copy
// ---------------------------------------------------------------------------
__global__ __launch_bounds__(256) void k_rel(const float* __restrict__ xm,
                                             const float* __restrict__ W1,
                                             const float* __restrict__ b1,
                                             const float* __restrict__ W2,
                                             const float* __restrict__ b2,
                                             float* __restrict__ rel,
                                             const float* __restrict__ W3,
                                             const float* __restrict__ b3,
                                             float* __restrict__ w3t,
                                             float* __restrict__ b3f) {
    int tid = threadIdx.x;
    if (blockIdx.x >= BB) {
        int idx = (blockIdx.x - BB) * 256 + tid;
        if (idx < OO * CC) {
            int o = idx / CC, c = idx % CC;
            w3t[c * OO + o] = W3[idx];
        }
        if (idx < OO) b3f[idx] = b3[idx];
        return;
    }
    __shared__ float x1s[RR][VV];
    __shared__ float x2s[RR][VV];
    int b = blockIdx.x;
    for (int idx = tid; idx < RR * VV; idx += 256) {
        int r = idx / VV, v = idx % VV;
        float s1 = b1[r], s2 = b2[r];
        for (int c = 0; c < CC; c++) {
            float xv = xm[(b * CC + c) * VV + v];
            s1 += W1[r * CC + c] * xv;
            s2 += W2[r * CC + c] * xv;
        }
        x1s[r][v] = s1;
        x2s[r][v] = s2;
    }
    __syncthreads();
    float* relb = rel + (size_t)b * VV * VV * RR;
    for (int idx = tid; idx < VV * VV * RR; idx += 256) {
        int r = idx % RR;
        int i = (idx / RR) % VV;
        int v = idx / (RR * VV);
        relb[idx] = tanhf(x1s[r][v] - x2s[r][i]);   // idx == (v*25+i)*8 + r
    }
}

// ---------------------------------------------------------------------------
// Kernel 3 (MFMA): z[b,c,t,i] = sum_{v,s} x[b,c,t+s-8,v] * Ad[s,v,i] -> bf16
//   Per (b,c) block: 9 taps x (8 m-tiles x 2 n-tiles) of 16x16x32 bf16 MFMA.
//   xpadB[t'][v]: bf16, row stride 40 (80 B, 16B-aligned, 2-way banks = free).
//   AdbS[s][i][v]: bf16, row stride 40. v>=25 and t'<8 zero-padded.
// ---------------------------------------------------------------------------
__global__ __launch_bounds__(256) void k_z(const float* __restrict__ x,
                                           const float* __restrict__ Ag,
                                           const float* __restrict__ W4,
                                           const float* __restrict__ b4,
                                           const float* __restrict__ rel,
                                           bf16* __restrict__ zws) {
    __shared__ __align__(16) unsigned short xpadB[136 * 40];     // 10880 B
    __shared__ __align__(16) unsigned short AdbS[TS_ * 32 * 40]; // 23040 B
    __shared__ float w4l[TS_][RR];
    __shared__ float b4l[TS_];

    int tid = threadIdx.x;
    int bc = blockIdx.x;
    int b = bc / CC, c = bc % CC;

    // ---- phase 0: weights to LDS, zero padding regions, stage x as bf16 ----
    if (tid < TS_ * RR)
        w4l[tid / RR][tid % RR] = W4[(c * TS_ + tid / RR) * RR + tid % RR];
    if (tid < TS_) b4l[tid] = b4[c * TS_ + tid];

    // xpadB rows 0..7, cols 0..31 = 0   (uint writes, row = 20 uints)
    if (tid < 128) ((unsigned int*)xpadB)[(tid >> 4) * 20 + (tid & 15)] = 0u;
    // xpadB rows 8..135, cols 25..31 = 0
    for (int id = tid; id < 128 * 7; id += 256) {
        int r = 8 + id / 7, v = 25 + id % 7;
        xpadB[r * 40 + v] = 0;
    }
    // AdbS: i<25, v=25..31 zero
    for (int id = tid; id < TS_ * 25 * 7; id += 256) {
        int s = id / 175, rem = id % 175;
        int i = rem / 7, v = 25 + rem % 7;
        AdbS[(s * 32 + i) * 40 + v] = 0;
    }
    // AdbS: i=25..31, cols 0..31 zero (uint writes)
    for (int id = tid; id < TS_ * 7 * 16; id += 256) {
        int s = id / 112, rem = id % 112;
        int i = 25 + rem / 16, u = rem % 16;
        ((unsigned int*)AdbS)[(s * 32 + i) * 20 + u] = 0u;
    }
    // fill xpadB from x (fp32 -> bf16), t' = t + 8
    const float4* xg4 = (const float4*)(x + (size_t)bc * TT_ * VV);
    for (int i4 = tid; i4 < TT_ * VV / 4; i4 += 256) {
        float4 f = xg4[i4];
        int idx = i4 * 4;
        float fe[4] = {f.x, f.y, f.z, f.w};
        #pragma unroll
        for (int e = 0; e < 4; e++) {
            int t = (idx + e) / VV, v = (idx + e) % VV;
            xpadB[(t + 8) * 40 + v] = f2b(fe[e]);
        }
    }
    __syncthreads();

    // ---- phase 1: Ad compute (fp32) -> AdbS bf16 ----
    const float* relb = rel + (size_t)b * VV * VV * RR;
    for (int task = tid; task < VV * VV; task += 256) {
        int v = task / VV, i = task % VV;
        const float4* r4 = (const float4*)(relb + (size_t)task * RR);
        float4 ra = r4[0], rb_ = r4[1];
        float av = Ag[task];
        #pragma unroll
        for (int s = 0; s < TS_; s++) {
            float a2 = b4l[s] + av;
            a2 += w4l[s][0] * ra.x + w4l[s][1] * ra.y + w4l[s][2] * ra.z + w4l[s][3] * ra.w;
            a2 += w4l[s][4] * rb_.x + w4l[s][5] * rb_.y + w4l[s][6] * rb_.z + w4l[s][7] * rb_.w;
            AdbS[(s * 32 + i) * 40 + v] = f2b(a2);
        }
    }
    __syncthreads();

    // ---- phase 2: MFMA GEMM. wave w -> m-tiles {2w, 2w+1}, n-tiles {0,1} ----
    int lane = tid & 63, wv = tid >> 6;
    int ml = lane & 15, qd = lane >> 4;
    f32x4 acc00 = {0.f, 0.f, 0.f, 0.f};
    f32x4 acc01 = acc00, acc10 = acc00, acc11 = acc00;
    int rowA0 = (wv * 2) * 16 + ml;       // logical t' base of m-tile 0 (+s per tap)
    #pragma unroll
    for (int s = 0; s < TS_; s++) {
        short8 a0 = *(const short8*)&xpadB[(rowA0 + s) * 40 + qd * 8];
        short8 a1 = *(const short8*)&xpadB[(rowA0 + 16 + s) * 40 + qd * 8];
        short8 b0 = *(const short8*)&AdbS[(s * 32 + ml) * 40 + qd * 8];
        short8 b1 = *(const short8*)&AdbS[(s * 32 + 16 + ml) * 40 + qd * 8];
        acc00 = __builtin_amdgcn_mfma_f32_16x16x32_bf16(a0, b0, acc00, 0, 0, 0);
        acc01 = __builtin_amdgcn_mfma_f32_16x16x32_bf16(a0, b1, acc01, 0, 0, 0);
        acc10 = __builtin_amdgcn_mfma_f32_16x16x32_bf16(a1, b0, acc10, 0, 0, 0);
        acc11 = __builtin_amdgcn_mfma_f32_16x16x32_bf16(a1, b1, acc11, 0, 0, 0);
    }

    // ---- store: C/D layout col=lane&15 (=i), row=qd*4+reg (=t in tile) ----
    bf16* zb = zws + (size_t)bc * TT_ * VV;
    int t0 = (wv * 2) * 16 + qd * 4;
    int i0 = ml, i1 = 16 + ml;
    #pragma unroll
    for (int r = 0; r < 4; r++) {
        zb[(t0 + r) * VV + i0]      = __float2bfloat16(acc00[r]);
        zb[(t0 + 16 + r) * VV + i0] = __float2bfloat16(acc10[r]);
    }
    if (i1 < VV) {
        #pragma unroll
        for (int r = 0; r < 4; r++) {
            zb[(t0 + r) * VV + i1]      = __float2bfloat16(acc01[r]);
            zb[(t0 + 16 + r) * VV + i1] = __float2bfloat16(acc11[r]);
        }
    }
}

// ---------------------------------------------------------------------------
// Kernel 4: out[b,o,t,j] = sum_c W3[o,c]*z[b,c,t,j] + b3[o]   -> FP32 out
// ---------------------------------------------------------------------------
__global__ __launch_bounds__(256) void k_conv3(const bf16* __restrict__ zws,
                                               const float* __restrict__ w3t,
                                               const float* __restrict__ b3f,
                                               float* __restrict__ out) {
    __shared__ float zl[CC][128];    // 32 KB
    __shared__ float w3l[CC * OO];   // 16 KB, [c][o]
    int tid = threadIdx.x;
    int b = blockIdx.x / 25, tile = blockIdx.x % 25;
    int tj0 = tile * 128;

    for (int idx = tid; idx < CC * OO; idx += 256) w3l[idx] = w3t[idx];
    for (int idx = tid; idx < CC * 128; idx += 256) {
        int c = idx >> 7, j = idx & 127;
        zl[c][j] = __bfloat162float(zws[(size_t)(b * CC + c) * (TT_ * VV) + tj0 + j]);
    }
    __syncthreads();

    int og = tid >> 5, tg = tid & 31;    // 8 o-groups x 32 tj-groups
    int o0 = og * 8, j0 = tg * 4;
    float accv[8][4];
    #pragma unroll
    for (int a = 0; a < 8; a++)
        #pragma unroll
        for (int q = 0; q < 4; q++) accv[a][q] = 0.f;

    for (int c = 0; c < CC; c++) {
        float4 zv = *(const float4*)&zl[c][j0];
        float4 wa = *(const float4*)&w3l[c * OO + o0];
        float4 wb = *(const float4*)&w3l[c * OO + o0 + 4];
        float zq[4] = {zv.x, zv.y, zv.z, zv.w};
        float wo[8] = {wa.x, wa.y, wa.z, wa.w, wb.x, wb.y, wb.z, wb.w};
        #pragma unroll
        for (int a = 0; a < 8; a++)
            #pragma unroll
            for (int q = 0; q < 4; q++) accv[a][q] += wo[a] * zq[q];
    }

    #pragma unroll
    for (int a = 0; a < 8; a++) {
        int o = o0 + a;
        float bo = b3f[o];
        float4 res;
        res.x = accv[a][0] + bo;
        res.y = accv[a][1] + bo;
        res.z = accv[a][2] + bo;
        res.w = accv[a][3] + bo;
        *(float4*)(out + ((size_t)(b * OO + o)) * (TT_ * VV) + tj0 + j0) = res;
    }
}

// ---------------------------------------------------------------------------
extern "C" void kernel_launch(void* const* d_in, const int* in_sizes, int n_in,
                              void* d_out, int out_size, void* d_ws, size_t ws_size,
                              hipStream_t stream) {
    const float* x  = (const float*)d_in[0];
    const float* A  = (const float*)d_in[1];
    const float* W1 = (const float*)d_in[2];
    const float* b1 = (const float*)d_in[3];
    const float* W2 = (const float*)d_in[4];
    const float* b2 = (const float*)d_in[5];
    const float* W4 = (const float*)d_in[6];
    const float* b4 = (const float*)d_in[7];
    const float* W3 = (const float*)d_in[8];
    const float* b3 = (const float*)d_in[9];
    float* out = (float*)d_out;

    // workspace layout (bytes)
    char* ws = (char*)d_ws;
    float* xm   = (float*)(ws);                         // 102400 * 4
    float* rel  = (float*)(ws + 409600);                // 320000 * 4
    float* w3t  = (float*)(ws + 1689600);               // 4096 * 4
    float* b3f  = (float*)(ws + 1705984);               // 64 * 4
    bf16*  zws  = (bf16*)(ws + 1706240);                // 13107200 * 2

    k_mean <<<BB * CC, 256, 0, stream>>>(x, xm);
    k_rel  <<<BB + 16, 256, 0, stream>>>(xm, W1, b1, W2, b2, rel, W3, b3, w3t, b3f);
    k_z    <<<BB * CC, 256, 0, stream>>>(x, A, W4, b4, rel, zws);
    k_conv3<<<BB * 25, 256, 0, stream>>>(zws, w3t, b3f, out);
}

// Round 6
// 174.021 us; speedup vs baseline: 1.6793x; 1.1196x over previous
//
#include <hip/hip_runtime.h>
#include <hip/hip_bf16.h>

#define BB 64
#define CC 64
#define TT_ 128
#define VV 25
#define RR 8
#define TS_ 9
#define OO 64

typedef __hip_bfloat16 bf16;
typedef __attribute__((ext_vector_type(8))) short short8;
typedef __attribute__((ext_vector_type(4))) float f32x4;

__device__ __forceinline__ unsigned short f2b(float f) {
    bf16 h = __float2bfloat16(f);
    return __builtin_bit_cast(unsigned short, h);
}

// ---------------------------------------------------------------------------
// Kernel 1: xm[b,c,v] = mean over t of x[b,c,t,v]. Block per (b,c), coalesced.
// ---------------------------------------------------------------------------
__global__ __launch_bounds__(256) void k_mean(const float* __restrict__ x,
                                              float* __restrict__ xm) {
    __shared__ float sm[256];
    int bc = blockIdx.x;
    int tid = threadIdx.x;
    const float* p = x + (size_t)bc * TT_ * VV;
    float s = 0.f;
    if (tid < 250) {
        for (int off = tid; off < TT_ * VV; off += 250) s += p[off];
    }
    sm[tid] = s;
    __syncthreads();
    if (tid < VV) {
        float tot = 0.f;
        #pragma unroll
        for (int g = 0; g < 10; g++) tot += sm[g * VV + tid];
        xm[bc * VV + tid] = tot * (1.0f / TT_);
    }
}

// ---------------------------------------------------------------------------
// Kernel 2: rel[b][v][i][r] = tanh(x1[b,r,v] - x2[b,r,i])   (fp32)
// ---------------------------------------------------------------------------
__global__ __launch_bounds__(256) void k_rel(const float* __restrict__ xm,
                                             const float* __restrict__ W1,
                                             const float* __restrict__ b1,
                                             const float* __restrict__ W2,
                                             const float* __restrict__ b2,
                                             float* __restrict__ rel) {
    __shared__ float x1s[RR][VV];
    __shared__ float x2s[RR][VV];
    int b = blockIdx.x, tid = threadIdx.x;
    for (int idx = tid; idx < RR * VV; idx += 256) {
        int r = idx / VV, v = idx % VV;
        float s1 = b1[r], s2 = b2[r];
        for (int c = 0; c < CC; c++) {
            float xv = xm[(b * CC + c) * VV + v];
            s1 += W1[r * CC + c] * xv;
            s2 += W2[r * CC + c] * xv;
        }
        x1s[r][v] = s1;
        x2s[r][v] = s2;
    }
    __syncthreads();
    float* relb = rel + (size_t)b * VV * VV * RR;
    for (int idx = tid; idx < VV * VV * RR; idx += 256) {
        int r = idx % RR;
        int i = (idx / RR) % VV;
        int v = idx / (RR * VV);
        relb[idx] = tanhf(x1s[r][v] - x2s[r][i]);   // idx == (v*25+i)*8 + r
    }
}

// ---------------------------------------------------------------------------
// Kernel 3 (MFMA): z[b,c,t,i] = sum_{v,s} x[b,c,t+s-8,v] * Ad[s,v,i] -> bf16
//   Single-barrier: [stage x->bf16 LDS, zero pads, Ad compute] | barrier | MFMA.
//   W4/b4 reads are block-uniform -> scalar loads (no LDS staging needed).
// ---------------------------------------------------------------------------
__global__ __launch_bounds__(256) void k_z(const float* __restrict__ x,
                                           const float* __restrict__ Ag,
                                           const float* __restrict__ W4,
                                           const float* __restrict__ b4,
                                           const float* __restrict__ rel,
                                           bf16* __restrict__ zws) {
    __shared__ __align__(16) unsigned short xpadB[136 * 40];     // 10880 B
    __shared__ __align__(16) unsigned short AdbS[TS_ * 32 * 40]; // 23040 B

    int tid = threadIdx.x;
    int bc = blockIdx.x;
    int b = bc / CC, c = bc % CC;

    // xpadB rows 0..7, cols 0..31 = 0 (t'<8 causal pad; cols 32..39 never read)
    if (tid < 128) ((unsigned int*)xpadB)[(tid >> 4) * 20 + (tid & 15)] = 0u;
    // xpadB rows 8..135, cols 25..31 = 0 (v pad)
    for (int id = tid; id < 128 * 7; id += 256) {
        int r = 8 + id / 7, v = 25 + id % 7;
        xpadB[r * 40 + v] = 0;
    }
    // AdbS: i<25 rows, v=25..31 = 0 (k pad; i>=25 rows feed discarded lanes only)
    for (int id = tid; id < TS_ * 25 * 7; id += 256) {
        int s = id / 175, rem = id % 175;
        int i = rem / 7, v = 25 + rem % 7;
        AdbS[(s * 32 + i) * 40 + v] = 0;
    }
    // stage x (fp32 -> bf16), t' = t + 8
    const float4* xg4 = (const float4*)(x + (size_t)bc * TT_ * VV);
    for (int i4 = tid; i4 < TT_ * VV / 4; i4 += 256) {
        float4 f = xg4[i4];
        int idx = i4 * 4;
        float fe[4] = {f.x, f.y, f.z, f.w};
        #pragma unroll
        for (int e = 0; e < 4; e++) {
            int t = (idx + e) / VV, v = (idx + e) % VV;
            xpadB[(t + 8) * 40 + v] = f2b(fe[e]);
        }
    }

    // Ad compute (fp32) -> AdbS bf16; W4/b4 block-uniform scalar loads
    const float* relb = rel + (size_t)b * VV * VV * RR;
    const float* W4c = W4 + c * TS_ * RR;
    const float* b4c = b4 + c * TS_;
    for (int task = tid; task < VV * VV; task += 256) {
        int v = task / VV, i = task % VV;
        const float4* r4 = (const float4*)(relb + (size_t)task * RR);
        float4 ra = r4[0], rb_ = r4[1];
        float av = Ag[task];
        #pragma unroll
        for (int s = 0; s < TS_; s++) {
            float a2 = b4c[s] + av;
            a2 += W4c[s*8+0] * ra.x  + W4c[s*8+1] * ra.y
                + W4c[s*8+2] * ra.z  + W4c[s*8+3] * ra.w;
            a2 += W4c[s*8+4] * rb_.x + W4c[s*8+5] * rb_.y
                + W4c[s*8+6] * rb_.z + W4c[s*8+7] * rb_.w;
            AdbS[(s * 32 + i) * 40 + v] = f2b(a2);
        }
    }
    __syncthreads();

    // MFMA: wave wv -> m-tiles {2wv,2wv+1}, n-tiles {0,1}, 9 taps
    int lane = tid & 63, wv = tid >> 6;
    int ml = lane & 15, qd = lane >> 4;
    f32x4 acc00 = {0.f, 0.f, 0.f, 0.f};
    f32x4 acc01 = acc00, acc10 = acc00, acc11 = acc00;
    int rowA0 = (wv * 2) * 16 + ml;
    #pragma unroll
    for (int s = 0; s < TS_; s++) {
        short8 a0 = *(const short8*)&xpadB[(rowA0 + s) * 40 + qd * 8];
        short8 a1 = *(const short8*)&xpadB[(rowA0 + 16 + s) * 40 + qd * 8];
        short8 b0 = *(const short8*)&AdbS[(s * 32 + ml) * 40 + qd * 8];
        short8 b1 = *(const short8*)&AdbS[(s * 32 + 16 + ml) * 40 + qd * 8];
        acc00 = __builtin_amdgcn_mfma_f32_16x16x32_bf16(a0, b0, acc00, 0, 0, 0);
        acc01 = __builtin_amdgcn_mfma_f32_16x16x32_bf16(a0, b1, acc01, 0, 0, 0);
        acc10 = __builtin_amdgcn_mfma_f32_16x16x32_bf16(a1, b0, acc10, 0, 0, 0);
        acc11 = __builtin_amdgcn_mfma_f32_16x16x32_bf16(a1, b1, acc11, 0, 0, 0);
    }

    bf16* zb = zws + (size_t)bc * TT_ * VV;
    int t0 = (wv * 2) * 16 + qd * 4;
    int i0 = ml, i1 = 16 + ml;
    #pragma unroll
    for (int r = 0; r < 4; r++) {
        zb[(t0 + r) * VV + i0]      = __float2bfloat16(acc00[r]);
        zb[(t0 + 16 + r) * VV + i0] = __float2bfloat16(acc10[r]);
    }
    if (i1 < VV) {
        #pragma unroll
        for (int r = 0; r < 4; r++) {
            zb[(t0 + r) * VV + i1]      = __float2bfloat16(acc01[r]);
            zb[(t0 + 16 + r) * VV + i1] = __float2bfloat16(acc11[r]);
        }
    }
}

// ---------------------------------------------------------------------------
// Kernel 4 (MFMA): out[b,o,tj] = sum_c W3[o,c]*z[b,c,tj] + b3[o]  -> fp32
//   Per (b, tj-tile of 128): M=64(o) N=128(tj) K=64(c), 64 MFMA.
//   A = W3 native [o][c] layout (bf16, stride 72: conflict-free b128).
//   B gathered from natural zl[c][tj] (stride 130: bank = 8qd+ml/2, free).
// ---------------------------------------------------------------------------
__global__ __launch_bounds__(256) void k_conv3(const bf16* __restrict__ zws,
                                               const float* __restrict__ W3,
                                               const float* __restrict__ b3,
                                               float* __restrict__ out) {
    __shared__ __align__(16) unsigned short w3b[OO * 72];   // 9216 B
    __shared__ __align__(16) unsigned short zl[CC * 130];   // 16640 B
    __shared__ float b3l[OO];
    int tid = threadIdx.x;
    int b = blockIdx.x / 25, tile = blockIdx.x % 25;
    int tj0 = tile * 128;

    if (tid < OO) b3l[tid] = b3[tid];
    // W3 [o][c] fp32 -> bf16 LDS (A operand, k-contiguous)
    for (int idx = tid; idx < OO * CC; idx += 256) {
        int o = idx >> 6, c = idx & 63;
        w3b[o * 72 + c] = f2b(W3[idx]);
    }
    // z tile: natural [c][j] layout, packed uint copies (coalesced, conflict-free)
    const unsigned int* zg = (const unsigned int*)(zws + (size_t)b * CC * (TT_ * VV));
    for (int idu = tid; idu < CC * 64; idu += 256) {
        int c = idu >> 6, ju = idu & 63;
        ((unsigned int*)zl)[c * 65 + ju] = zg[c * 1600 + (tj0 >> 1) + ju];
    }
    __syncthreads();

    int lane = tid & 63, wv = tid >> 6;
    int ml = lane & 15, qd = lane >> 4;
    f32x4 acc[4][2];
    #pragma unroll
    for (int m = 0; m < 4; m++)
        #pragma unroll
        for (int nl = 0; nl < 2; nl++) acc[m][nl] = (f32x4){0.f, 0.f, 0.f, 0.f};

    #pragma unroll
    for (int k0 = 0; k0 < 2; k0++) {
        short8 a[4];
        #pragma unroll
        for (int m = 0; m < 4; m++)
            a[m] = *(const short8*)&w3b[(m * 16 + ml) * 72 + k0 * 32 + qd * 8];
        #pragma unroll
        for (int nl = 0; nl < 2; nl++) {
            int col = (2 * wv + nl) * 16 + ml;
            int cb = k0 * 32 + qd * 8;
            short8 bf;
            #pragma unroll
            for (int j = 0; j < 8; j++)
                bf[j] = (short)zl[(cb + j) * 130 + col];
            #pragma unroll
            for (int m = 0; m < 4; m++)
                acc[m][nl] = __builtin_amdgcn_mfma_f32_16x16x32_bf16(a[m], bf, acc[m][nl], 0, 0, 0);
        }
    }

    float* ob = out + (size_t)b * OO * (TT_ * VV) + tj0;
    #pragma unroll
    for (int m = 0; m < 4; m++)
        #pragma unroll
        for (int nl = 0; nl < 2; nl++) {
            int col = (2 * wv + nl) * 16 + ml;
            #pragma unroll
            for (int r = 0; r < 4; r++) {
                int o = m * 16 + qd * 4 + r;
                ob[(size_t)o * (TT_ * VV) + col] = acc[m][nl][r] + b3l[o];
            }
        }
}

// ---------------------------------------------------------------------------
extern "C" void kernel_launch(void* const* d_in, const int* in_sizes, int n_in,
                              void* d_out, int out_size, void* d_ws, size_t ws_size,
                              hipStream_t stream) {
    const float* x  = (const float*)d_in[0];
    const float* A  = (const float*)d_in[1];
    const float* W1 = (const float*)d_in[2];
    const float* b1 = (const float*)d_in[3];
    const float* W2 = (const float*)d_in[4];
    const float* b2 = (const float*)d_in[5];
    const float* W4 = (const float*)d_in[6];
    const float* b4 = (const float*)d_in[7];
    const float* W3 = (const float*)d_in[8];
    const float* b3 = (const float*)d_in[9];
    float* out = (float*)d_out;

    char* ws = (char*)d_ws;
    float* xm   = (float*)(ws);                         // 102400 * 4
    float* rel  = (float*)(ws + 409600);                // 320000 * 4
    bf16*  zws  = (bf16*)(ws + 1689600);                // 13107200 * 2

    k_mean <<<BB * CC, 256, 0, stream>>>(x, xm);
    k_rel  <<<BB,      256, 0, stream>>>(xm, W1, b1, W2, b2, rel);
    k_z    <<<BB * CC, 256, 0, stream>>>(x, A, W4, b4, rel, zws);
    k_conv3<<<BB * 25, 256, 0, stream>>>(zws, W3, b3, out);
}